// Round 2
// baseline (592.270 us; speedup 1.0000x reference)
//
#include <hip/hip_runtime.h>
#include <hip/hip_bf16.h>

// GIPA wide conv: h=XWn; e=EWe; score=leaky(dot_head(h[src],e)/sqrt(32));
// softmax over dst; out = segsum(h[src]*attn).
// Inputs/outputs fp32; MFMA operands converted to bf16 on the fly; fp32 accum.

#define NN 50000
#define NE 800000
#define NCHUNK 196        // ceil(NN/256)

typedef __bf16 bf16x8 __attribute__((ext_vector_type(8)));
typedef float f32x4 __attribute__((ext_vector_type(4)));

static __device__ __forceinline__ f32x4 mfma16(bf16x8 a, bf16x8 b, f32x4 c) {
  return __builtin_amdgcn_mfma_f32_16x16x32_bf16(a, b, c, 0, 0, 0);
}

static __device__ __forceinline__ bf16x8 cvt8(const float* p) {
  float4 a = *(const float4*)p;
  float4 b = *(const float4*)(p + 4);
  bf16x8 r;
  r[0] = (__bf16)a.x; r[1] = (__bf16)a.y; r[2] = (__bf16)a.z; r[3] = (__bf16)a.w;
  r[4] = (__bf16)b.x; r[5] = (__bf16)b.y; r[6] = (__bf16)b.z; r[7] = (__bf16)b.w;
  return r;
}

// ---- K0: transpose + fp32->bf16 weights ----
// WtN[col][k] (128x256), WtE[col][k] (128x64)
__global__ __launch_bounds__(256) void k_transpose_w(const float* __restrict__ Wn,
                                                     const float* __restrict__ We,
                                                     __bf16* __restrict__ WtN,
                                                     __bf16* __restrict__ WtE) {
  int t = blockIdx.x * 256 + threadIdx.x;
  if (t < 128 * 256) {
    int col = t >> 8, k = t & 255;
    WtN[t] = (__bf16)Wn[k * 128 + col];
  } else {
    int o = t - 128 * 256;            // 0..8191
    int col = o >> 6, k = o & 63;
    WtE[o] = (__bf16)We[k * 128 + col];
  }
}

// ---- K1: node projection h[NN][128] fp32 via MFMA ----
// block=256 (4 waves). wave w -> cols [w*32, w*32+32). 5 groups of 16 nodes/block.
__global__ __launch_bounds__(256) void k_node_proj(const float* __restrict__ nf,
                                                   const __bf16* __restrict__ WtN,
                                                   float* __restrict__ h) {
  int tid = threadIdx.x;
  int w = tid >> 6, lane = tid & 63, q = lane >> 4, c = lane & 15;
  int colbase = w * 32;
  bf16x8 bf[2][8];
#pragma unroll
  for (int nt = 0; nt < 2; ++nt)
#pragma unroll
    for (int ks = 0; ks < 8; ++ks)
      bf[nt][ks] = *(const bf16x8*)&WtN[(colbase + nt * 16 + c) * 256 + ks * 32 + q * 8];

  for (int g = 0; g < 5; ++g) {
    int gbase = (blockIdx.x * 5 + g) * 16;            // exact: 625*5*16 = 50000
    const float* arow = nf + (size_t)(gbase + c) * 256 + q * 8;
    bf16x8 af[8];
#pragma unroll
    for (int ks = 0; ks < 8; ++ks) af[ks] = cvt8(arow + ks * 32);
    f32x4 acc0 = {0.f, 0.f, 0.f, 0.f}, acc1 = acc0;
#pragma unroll
    for (int ks = 0; ks < 8; ++ks) {
      acc0 = mfma16(af[ks], bf[0][ks], acc0);
      acc1 = mfma16(af[ks], bf[1][ks], acc1);
    }
#pragma unroll
    for (int reg = 0; reg < 4; ++reg) {
      int node = gbase + q * 4 + reg;
      h[(size_t)node * 128 + colbase + c]      = acc0[reg];
      h[(size_t)node * 128 + colbase + 16 + c] = acc1[reg];
    }
  }
}

// ---- K2: degree histogram ----
__global__ __launch_bounds__(256) void k_degree(const int* __restrict__ dst, int* __restrict__ deg) {
  int e = blockIdx.x * 256 + threadIdx.x;              // exact: 3125*256 = 800000
  atomicAdd(&deg[dst[e]], 1);
}

// ---- K3a: per-chunk sums ----
__global__ __launch_bounds__(256) void k_chunk_sum(const int* __restrict__ deg, int* __restrict__ csum) {
  int b = blockIdx.x, t = threadIdx.x;
  int i = b * 256 + t;
  int v = (i < NN) ? deg[i] : 0;
#pragma unroll
  for (int off = 32; off; off >>= 1) v += __shfl_xor(v, off, 64);
  __shared__ int sw[4];
  if ((t & 63) == 0) sw[t >> 6] = v;
  __syncthreads();
  if (t == 0) csum[b] = sw[0] + sw[1] + sw[2] + sw[3];
}

// ---- K3b: scan chunk sums (1 block) ----
__global__ __launch_bounds__(256) void k_scan_chunks(const int* __restrict__ csum,
                                                     int* __restrict__ coff, int* __restrict__ rowptr) {
  int t = threadIdx.x;
  __shared__ int s[256];
  int v = (t < NCHUNK) ? csum[t] : 0;
  s[t] = v;
  __syncthreads();
  for (int off = 1; off < 256; off <<= 1) {
    int x = (t >= off) ? s[t - off] : 0;
    __syncthreads();
    s[t] += x;
    __syncthreads();
  }
  if (t < NCHUNK) coff[t] = s[t] - v;   // exclusive
  if (t == 0) rowptr[NN] = NE;
}

// ---- K3c: final exclusive scan -> rowptr, fill ----
__global__ __launch_bounds__(256) void k_scan_final(const int* __restrict__ deg, const int* __restrict__ coff,
                                                    int* __restrict__ rowptr, int* __restrict__ fill) {
  int b = blockIdx.x, t = threadIdx.x;
  int i = b * 256 + t;
  int v = (i < NN) ? deg[i] : 0;
  __shared__ int s[256];
  s[t] = v;
  __syncthreads();
  for (int off = 1; off < 256; off <<= 1) {
    int x = (t >= off) ? s[t - off] : 0;
    __syncthreads();
    s[t] += x;
    __syncthreads();
  }
  if (i < NN) {
    int excl = s[t] - v + coff[b];
    rowptr[i] = excl;
    fill[i] = excl;
  }
}

// ---- K4: scatter edge ids by dst ----
__global__ __launch_bounds__(256) void k_scatter(const int* __restrict__ dst, int* __restrict__ fill,
                                                 int* __restrict__ eids) {
  int e = blockIdx.x * 256 + threadIdx.x;
  int p = atomicAdd(&fill[dst[e]], 1);
  eids[p] = e;
}

// ---- K5: fused edge projection + score (MFMA) ----
// block=256, 10 groups of 64 edges (wave handles 16). exact: 1250*640 = 800000.
__global__ __launch_bounds__(256) void k_edge_score(const float* __restrict__ ef,
                                                    const __bf16* __restrict__ WtE,
                                                    const float* __restrict__ h,
                                                    const int* __restrict__ src,
                                                    float* __restrict__ score) {
  int tid = threadIdx.x;
  int w = tid >> 6, lane = tid & 63, q = lane >> 4, c = lane & 15;
  bf16x8 bf[8][2];
#pragma unroll
  for (int nt = 0; nt < 8; ++nt)
#pragma unroll
    for (int ks = 0; ks < 2; ++ks)
      bf[nt][ks] = *(const bf16x8*)&WtE[(nt * 16 + c) * 64 + ks * 32 + q * 8];

  for (int g = 0; g < 10; ++g) {
    int ebase = blockIdx.x * 640 + g * 64 + w * 16;
    const float* arow = ef + (size_t)(ebase + c) * 64 + q * 8;
    bf16x8 af0 = cvt8(arow);
    bf16x8 af1 = cvt8(arow + 32);
    f32x4 acc[8];
#pragma unroll
    for (int nt = 0; nt < 8; ++nt) acc[nt] = (f32x4){0.f, 0.f, 0.f, 0.f};
#pragma unroll
    for (int nt = 0; nt < 8; ++nt) acc[nt] = mfma16(af0, bf[nt][0], acc[nt]);
#pragma unroll
    for (int nt = 0; nt < 8; ++nt) acc[nt] = mfma16(af1, bf[nt][1], acc[nt]);

    int srow[4];
#pragma unroll
    for (int reg = 0; reg < 4; ++reg) srow[reg] = src[ebase + q * 4 + reg];

    float p[4][4];   // [reg][head]
#pragma unroll
    for (int r = 0; r < 4; ++r)
#pragma unroll
      for (int hd = 0; hd < 4; ++hd) p[r][hd] = 0.f;

#pragma unroll
    for (int nt = 0; nt < 8; ++nt) {
      int head = nt >> 1;
      const float* hp = h + nt * 16 + c;
#pragma unroll
      for (int reg = 0; reg < 4; ++reg)
        p[reg][head] += acc[nt][reg] * hp[(size_t)srow[reg] * 128];
    }
    // reduce over the 16 col-lanes (lane bits 0..3)
#pragma unroll
    for (int off = 1; off <= 8; off <<= 1)
#pragma unroll
      for (int reg = 0; reg < 4; ++reg)
#pragma unroll
        for (int hd = 0; hd < 4; ++hd)
          p[reg][hd] += __shfl_xor(p[reg][hd], off, 64);

    if (c == 0) {
      const float sc = 0.17677669529663687f;   // 1/sqrt(32)
#pragma unroll
      for (int reg = 0; reg < 4; ++reg) {
        int e = ebase + q * 4 + reg;
        float a0 = p[reg][0] * sc, a1 = p[reg][1] * sc, a2 = p[reg][2] * sc, a3 = p[reg][3] * sc;
        float4 s;
        s.x = a0 > 0.f ? a0 : 0.01f * a0;
        s.y = a1 > 0.f ? a1 : 0.01f * a1;
        s.z = a2 > 0.f ? a2 : 0.01f * a2;
        s.w = a3 > 0.f ? a3 : 0.01f * a3;
        *(float4*)&score[(size_t)e * 4] = s;
      }
    }
  }
}

// ---- K6: per-node online-softmax + aggregation (1 wave/node, no atomics) ----
__global__ __launch_bounds__(256) void k_aggregate(const int* __restrict__ rowptr,
                                                   const int* __restrict__ eids,
                                                   const int* __restrict__ src,
                                                   const float* __restrict__ score,
                                                   const float* __restrict__ h,
                                                   float* __restrict__ out) {
  int w = threadIdx.x >> 6, lane = threadIdx.x & 63;
  int n = blockIdx.x * 4 + w;                         // exact: 12500*4 = 50000
  int s0 = rowptr[n], s1 = rowptr[n + 1];
  int hsel = lane >> 5;                               // 0 or 1
  float m0 = -1e30f, m1 = -1e30f, l0 = 0.f, l1 = 0.f, a0 = 0.f, a1 = 0.f;
  for (int i = s0; i < s1; ++i) {
    int e = eids[i];
    float4 s4 = *(const float4*)&score[(size_t)e * 4];
    int sr = src[e];
    const float* hr = h + (size_t)sr * 128;
    float hv0 = hr[lane];
    float hv1 = hr[lane + 64];
    float sa = hsel ? s4.y : s4.x;                    // head 0/1 for col lane
    float sb = hsel ? s4.w : s4.z;                    // head 2/3 for col lane+64
    float mn0 = fmaxf(m0, sa);
    float e0 = __expf(m0 - mn0);
    float p0 = __expf(sa - mn0);
    l0 = l0 * e0 + p0;
    a0 = a0 * e0 + p0 * hv0;
    m0 = mn0;
    float mn1 = fmaxf(m1, sb);
    float e1 = __expf(m1 - mn1);
    float p1 = __expf(sb - mn1);
    l1 = l1 * e1 + p1;
    a1 = a1 * e1 + p1 * hv1;
    m1 = mn1;
  }
  float o0 = (s1 > s0) ? a0 / l0 : 0.f;
  float o1 = (s1 > s0) ? a1 / l1 : 0.f;
  out[(size_t)n * 128 + lane]      = o0;
  out[(size_t)n * 128 + 64 + lane] = o1;
}

extern "C" void kernel_launch(void* const* d_in, const int* in_sizes, int n_in,
                              void* d_out, int out_size, void* d_ws, size_t ws_size,
                              hipStream_t stream) {
  const float* node_feat = (const float*)d_in[0];   // [NN,256] fp32
  const float* edge_feat = (const float*)d_in[1];   // [NE,64]  fp32
  const int*   src       = (const int*)d_in[2];
  const int*   dst       = (const int*)d_in[3];
  const float* W_node    = (const float*)d_in[4];   // [256,128] fp32
  const float* W_edge    = (const float*)d_in[5];   // [64,128]  fp32
  float* out             = (float*)d_out;           // [NN,128] fp32

  char* ws = (char*)d_ws;
  // ws layout (bytes, 256-aligned)
  float*  h      = (float*)(ws + 0);                // 25,600,000
  float*  score  = (float*)(ws + 25600000);         // 12,800,000
  int*    eids   = (int*)  (ws + 38400000);         //  3,200,000
  int*    deg    = (int*)  (ws + 41600000);         //    200,000
  int*    rowptr = (int*)  (ws + 41800192);         //    200,004
  int*    fill   = (int*)  (ws + 42000896);         //    200,000
  int*    csum   = (int*)  (ws + 42201600);         //        784
  int*    coff   = (int*)  (ws + 42202624);         //        784
  __bf16* WtN    = (__bf16*)(ws + 42203648);        //     65,536
  __bf16* WtE    = (__bf16*)(ws + 42269184);        //     16,384

  hipMemsetAsync(deg, 0, NN * sizeof(int), stream);

  k_transpose_w<<<160, 256, 0, stream>>>(W_node, W_edge, WtN, WtE);
  k_node_proj  <<<625, 256, 0, stream>>>(node_feat, WtN, h);
  k_degree     <<<3125, 256, 0, stream>>>(dst, deg);
  k_chunk_sum  <<<NCHUNK, 256, 0, stream>>>(deg, csum);
  k_scan_chunks<<<1, 256, 0, stream>>>(csum, coff, rowptr);
  k_scan_final <<<NCHUNK, 256, 0, stream>>>(deg, coff, rowptr, fill);
  k_scatter    <<<3125, 256, 0, stream>>>(dst, fill, eids);
  k_edge_score <<<1250, 256, 0, stream>>>(edge_feat, WtE, h, src, score);
  k_aggregate  <<<12500, 256, 0, stream>>>(rowptr, eids, src, score, h, out);
}

// Round 3
// 533.060 us; speedup vs baseline: 1.1111x; 1.1111x over previous
//
#include <hip/hip_runtime.h>
#include <hip/hip_bf16.h>

// GIPA wide conv: h=XWn; e=EWe; score=leaky(dot_head(h[src],e)/sqrt(32));
// softmax over dst; out = segsum(h[src]*attn).
// Inputs/outputs fp32. h stored bf16 (halves gather traffic; error budget ok).
// MFMA operands bf16, fp32 accumulation.

#define NN 50000
#define NE 800000
#define NCHUNK 196        // ceil(NN/256)

typedef __bf16 bf16x8 __attribute__((ext_vector_type(8)));
typedef float f32x4 __attribute__((ext_vector_type(4)));

static __device__ __forceinline__ f32x4 mfma16(bf16x8 a, bf16x8 b, f32x4 c) {
  return __builtin_amdgcn_mfma_f32_16x16x32_bf16(a, b, c, 0, 0, 0);
}

static __device__ __forceinline__ bf16x8 cvt8(const float* p) {
  float4 a = *(const float4*)p;
  float4 b = *(const float4*)(p + 4);
  bf16x8 r;
  r[0] = (__bf16)a.x; r[1] = (__bf16)a.y; r[2] = (__bf16)a.z; r[3] = (__bf16)a.w;
  r[4] = (__bf16)b.x; r[5] = (__bf16)b.y; r[6] = (__bf16)b.z; r[7] = (__bf16)b.w;
  return r;
}

static __device__ __forceinline__ float bfbits(ushort u) {
  union { unsigned int i; float f; } v; v.i = ((unsigned int)u) << 16; return v.f;
}

// ---- K0: transpose + fp32->bf16 weights ----
__global__ __launch_bounds__(256) void k_transpose_w(const float* __restrict__ Wn,
                                                     const float* __restrict__ We,
                                                     __bf16* __restrict__ WtN,
                                                     __bf16* __restrict__ WtE) {
  int t = blockIdx.x * 256 + threadIdx.x;
  if (t < 128 * 256) {
    int col = t >> 8, k = t & 255;
    WtN[t] = (__bf16)Wn[k * 128 + col];
  } else {
    int o = t - 128 * 256;            // 0..8191
    int col = o >> 6, k = o & 63;
    WtE[o] = (__bf16)We[k * 128 + col];
  }
}

// ---- K1: node projection h[NN][128] bf16 via MFMA ----
__global__ __launch_bounds__(256) void k_node_proj(const float* __restrict__ nf,
                                                   const __bf16* __restrict__ WtN,
                                                   __bf16* __restrict__ h) {
  int tid = threadIdx.x;
  int w = tid >> 6, lane = tid & 63, q = lane >> 4, c = lane & 15;
  int colbase = w * 32;
  bf16x8 bf[2][8];
#pragma unroll
  for (int nt = 0; nt < 2; ++nt)
#pragma unroll
    for (int ks = 0; ks < 8; ++ks)
      bf[nt][ks] = *(const bf16x8*)&WtN[(colbase + nt * 16 + c) * 256 + ks * 32 + q * 8];

  for (int g = 0; g < 5; ++g) {
    int gbase = (blockIdx.x * 5 + g) * 16;            // exact: 625*5*16 = 50000
    const float* arow = nf + (size_t)(gbase + c) * 256 + q * 8;
    bf16x8 af[8];
#pragma unroll
    for (int ks = 0; ks < 8; ++ks) af[ks] = cvt8(arow + ks * 32);
    f32x4 acc0 = {0.f, 0.f, 0.f, 0.f}, acc1 = acc0;
#pragma unroll
    for (int ks = 0; ks < 8; ++ks) {
      acc0 = mfma16(af[ks], bf[0][ks], acc0);
      acc1 = mfma16(af[ks], bf[1][ks], acc1);
    }
#pragma unroll
    for (int reg = 0; reg < 4; ++reg) {
      int node = gbase + q * 4 + reg;
      h[(size_t)node * 128 + colbase + c]      = (__bf16)acc0[reg];
      h[(size_t)node * 128 + colbase + 16 + c] = (__bf16)acc1[reg];
    }
  }
}

// ---- K2: degree histogram ----
__global__ __launch_bounds__(256) void k_degree(const int* __restrict__ dst, int* __restrict__ deg) {
  int e = blockIdx.x * 256 + threadIdx.x;              // exact: 3125*256 = 800000
  atomicAdd(&deg[dst[e]], 1);
}

// ---- K3a: per-chunk sums ----
__global__ __launch_bounds__(256) void k_chunk_sum(const int* __restrict__ deg, int* __restrict__ csum) {
  int b = blockIdx.x, t = threadIdx.x;
  int i = b * 256 + t;
  int v = (i < NN) ? deg[i] : 0;
#pragma unroll
  for (int off = 32; off; off >>= 1) v += __shfl_xor(v, off, 64);
  __shared__ int sw[4];
  if ((t & 63) == 0) sw[t >> 6] = v;
  __syncthreads();
  if (t == 0) csum[b] = sw[0] + sw[1] + sw[2] + sw[3];
}

// ---- K3b: scan chunk sums (1 block) ----
__global__ __launch_bounds__(256) void k_scan_chunks(const int* __restrict__ csum,
                                                     int* __restrict__ coff, int* __restrict__ rowptr) {
  int t = threadIdx.x;
  __shared__ int s[256];
  int v = (t < NCHUNK) ? csum[t] : 0;
  s[t] = v;
  __syncthreads();
  for (int off = 1; off < 256; off <<= 1) {
    int x = (t >= off) ? s[t - off] : 0;
    __syncthreads();
    s[t] += x;
    __syncthreads();
  }
  if (t < NCHUNK) coff[t] = s[t] - v;   // exclusive
  if (t == 0) rowptr[NN] = NE;
}

// ---- K3c: final exclusive scan -> rowptr, fill ----
__global__ __launch_bounds__(256) void k_scan_final(const int* __restrict__ deg, const int* __restrict__ coff,
                                                    int* __restrict__ rowptr, int* __restrict__ fill) {
  int b = blockIdx.x, t = threadIdx.x;
  int i = b * 256 + t;
  int v = (i < NN) ? deg[i] : 0;
  __shared__ int s[256];
  s[t] = v;
  __syncthreads();
  for (int off = 1; off < 256; off <<= 1) {
    int x = (t >= off) ? s[t - off] : 0;
    __syncthreads();
    s[t] += x;
    __syncthreads();
  }
  if (i < NN) {
    int excl = s[t] - v + coff[b];
    rowptr[i] = excl;
    fill[i] = excl;
  }
}

// ---- K4: scatter edge ids by dst ----
__global__ __launch_bounds__(256) void k_scatter(const int* __restrict__ dst, int* __restrict__ fill,
                                                 int* __restrict__ eids) {
  int e = blockIdx.x * 256 + threadIdx.x;
  int p = atomicAdd(&fill[dst[e]], 1);
  eids[p] = e;
}

// ---- K5: fused edge projection + score (MFMA), h read as bf16 ----
__global__ __launch_bounds__(256) void k_edge_score(const float* __restrict__ ef,
                                                    const __bf16* __restrict__ WtE,
                                                    const __bf16* __restrict__ h,
                                                    const int* __restrict__ src,
                                                    float* __restrict__ score) {
  int tid = threadIdx.x;
  int w = tid >> 6, lane = tid & 63, q = lane >> 4, c = lane & 15;
  const ushort* hb = (const ushort*)h;
  bf16x8 bf[8][2];
#pragma unroll
  for (int nt = 0; nt < 8; ++nt)
#pragma unroll
    for (int ks = 0; ks < 2; ++ks)
      bf[nt][ks] = *(const bf16x8*)&WtE[(nt * 16 + c) * 64 + ks * 32 + q * 8];

  for (int g = 0; g < 10; ++g) {
    int ebase = blockIdx.x * 640 + g * 64 + w * 16;   // exact: 1250*640 = 800000
    const float* arow = ef + (size_t)(ebase + c) * 64 + q * 8;
    bf16x8 af0 = cvt8(arow);
    bf16x8 af1 = cvt8(arow + 32);
    f32x4 acc[8];
#pragma unroll
    for (int nt = 0; nt < 8; ++nt) acc[nt] = (f32x4){0.f, 0.f, 0.f, 0.f};
#pragma unroll
    for (int nt = 0; nt < 8; ++nt) acc[nt] = mfma16(af0, bf[nt][0], acc[nt]);
#pragma unroll
    for (int nt = 0; nt < 8; ++nt) acc[nt] = mfma16(af1, bf[nt][1], acc[nt]);

    int srow[4];
#pragma unroll
    for (int reg = 0; reg < 4; ++reg) srow[reg] = src[ebase + q * 4 + reg];

    float p[4][4];   // [reg][head]
#pragma unroll
    for (int r = 0; r < 4; ++r)
#pragma unroll
      for (int hd = 0; hd < 4; ++hd) p[r][hd] = 0.f;

#pragma unroll
    for (int nt = 0; nt < 8; ++nt) {
      int head = nt >> 1;
      const ushort* hp = hb + nt * 16 + c;
#pragma unroll
      for (int reg = 0; reg < 4; ++reg)
        p[reg][head] += acc[nt][reg] * bfbits(hp[(size_t)srow[reg] * 128]);
    }
    // reduce over the 16 col-lanes (lane bits 0..3)
#pragma unroll
    for (int off = 1; off <= 8; off <<= 1)
#pragma unroll
      for (int reg = 0; reg < 4; ++reg)
#pragma unroll
        for (int hd = 0; hd < 4; ++hd)
          p[reg][hd] += __shfl_xor(p[reg][hd], off, 64);

    if (c == 0) {
      const float sc = 0.17677669529663687f;   // 1/sqrt(32)
#pragma unroll
      for (int reg = 0; reg < 4; ++reg) {
        int e = ebase + q * 4 + reg;
        float a0 = p[reg][0] * sc, a1 = p[reg][1] * sc, a2 = p[reg][2] * sc, a3 = p[reg][3] * sc;
        float4 s;
        s.x = a0 > 0.f ? a0 : 0.01f * a0;
        s.y = a1 > 0.f ? a1 : 0.01f * a1;
        s.z = a2 > 0.f ? a2 : 0.01f * a2;
        s.w = a3 > 0.f ? a3 : 0.01f * a3;
        *(float4*)&score[(size_t)e * 4] = s;
      }
    }
  }
}

// ---- K6: per-node softmax + aggregation (1 wave/node, chunked, pipelined) ----
// Lane owns features {2*lane, 2*lane+1} -> single head = lane>>4 per lane.
__global__ __launch_bounds__(256) void k_aggregate(const int* __restrict__ rowptr,
                                                   const int* __restrict__ eids,
                                                   const int* __restrict__ src,
                                                   const float* __restrict__ score,
                                                   const __bf16* __restrict__ h,
                                                   float* __restrict__ out) {
  int w = threadIdx.x >> 6, lane = threadIdx.x & 63;
  int n = blockIdx.x * 4 + w;                         // exact: 12500*4 = 50000
  int s0 = rowptr[n], s1 = rowptr[n + 1];
  int head = lane >> 4;
  const unsigned int* h2 = (const unsigned int*)h;

  float m = -1e30f, l = 0.f, a0 = 0.f, a1 = 0.f;
  for (int c0 = s0; c0 < s1; c0 += 64) {
    int nc = s1 - c0; if (nc > 64) nc = 64;
    // bulk per-chunk loads into lane registers
    int el = (lane < nc) ? eids[c0 + lane] : 0;
    int srl = (lane < nc) ? src[el] : 0;
    float4 s4;
    if (lane < nc) s4 = *(const float4*)&score[(size_t)el * 4];
    else { s4.x = -1e30f; s4.y = -1e30f; s4.z = -1e30f; s4.w = -1e30f; }
    // chunk max per head via butterfly
    float4 mx = s4;
#pragma unroll
    for (int off = 1; off < 64; off <<= 1) {
      mx.x = fmaxf(mx.x, __shfl_xor(mx.x, off, 64));
      mx.y = fmaxf(mx.y, __shfl_xor(mx.y, off, 64));
      mx.z = fmaxf(mx.z, __shfl_xor(mx.z, off, 64));
      mx.w = fmaxf(mx.w, __shfl_xor(mx.w, off, 64));
    }
    float mc = (head == 0) ? mx.x : (head == 1) ? mx.y : (head == 2) ? mx.z : mx.w;
    float mn = fmaxf(m, mc);
    float t = __expf(m - mn);
    l *= t; a0 *= t; a1 *= t; m = mn;
    // pipelined inner loop (1-deep prefetch of score + h row)
    int e = __shfl(el, 0, 64), sr = __shfl(srl, 0, 64);
    float sc = score[(size_t)e * 4 + head];
    unsigned int hv = h2[(size_t)sr * 64 + lane];
    for (int j = 0; j < nc; ++j) {
      float sc_c = sc; unsigned int hv_c = hv;
      if (j + 1 < nc) {
        int e2 = __shfl(el, j + 1, 64), sr2 = __shfl(srl, j + 1, 64);
        sc = score[(size_t)e2 * 4 + head];
        hv = h2[(size_t)sr2 * 64 + lane];
      }
      float p = __expf(sc_c - m);
      union { unsigned int i; float f; } f0, f1;
      f0.i = hv_c << 16;
      f1.i = hv_c & 0xffff0000u;
      l += p;
      a0 = fmaf(p, f0.f, a0);
      a1 = fmaf(p, f1.f, a1);
    }
  }
  float inv = (s1 > s0) ? 1.f / l : 0.f;
  float2 o; o.x = a0 * inv; o.y = a1 * inv;
  ((float2*)out)[(size_t)n * 64 + lane] = o;
}

extern "C" void kernel_launch(void* const* d_in, const int* in_sizes, int n_in,
                              void* d_out, int out_size, void* d_ws, size_t ws_size,
                              hipStream_t stream) {
  const float* node_feat = (const float*)d_in[0];   // [NN,256] fp32
  const float* edge_feat = (const float*)d_in[1];   // [NE,64]  fp32
  const int*   src       = (const int*)d_in[2];
  const int*   dst       = (const int*)d_in[3];
  const float* W_node    = (const float*)d_in[4];   // [256,128] fp32
  const float* W_edge    = (const float*)d_in[5];   // [64,128]  fp32
  float* out             = (float*)d_out;           // [NN,128] fp32

  char* ws = (char*)d_ws;
  __bf16* h      = (__bf16*)(ws + 0);               // 12,800,000
  float*  score  = (float*) (ws + 12800000);        // 12,800,000
  int*    eids   = (int*)   (ws + 25600000);        //  3,200,000
  int*    deg    = (int*)   (ws + 28800000);        //    200,000
  int*    rowptr = (int*)   (ws + 29000192);        //    200,004
  int*    fill   = (int*)   (ws + 29200640);        //    200,000
  int*    csum   = (int*)   (ws + 29400832);        //        784
  int*    coff   = (int*)   (ws + 29401856);        //        784
  __bf16* WtN    = (__bf16*)(ws + 29402880);        //     65,536
  __bf16* WtE    = (__bf16*)(ws + 29468416);        //     16,384

  hipMemsetAsync(deg, 0, NN * sizeof(int), stream);

  k_transpose_w<<<160, 256, 0, stream>>>(W_node, W_edge, WtN, WtE);
  k_node_proj  <<<625, 256, 0, stream>>>(node_feat, WtN, h);
  k_degree     <<<3125, 256, 0, stream>>>(dst, deg);
  k_chunk_sum  <<<NCHUNK, 256, 0, stream>>>(deg, csum);
  k_scan_chunks<<<1, 256, 0, stream>>>(csum, coff, rowptr);
  k_scan_final <<<NCHUNK, 256, 0, stream>>>(deg, coff, rowptr, fill);
  k_scatter    <<<3125, 256, 0, stream>>>(dst, fill, eids);
  k_edge_score <<<1250, 256, 0, stream>>>(edge_feat, WtE, h, src, score);
  k_aggregate  <<<12500, 256, 0, stream>>>(rowptr, eids, src, score, h, out);
}